// Round 9
// baseline (155.265 us; speedup 1.0000x reference)
//
#include <hip/hip_runtime.h>
#include <hip/hip_bf16.h>

// ---------------------------------------------------------------------------
// PlainSelfAttention (2quad, tau-scaled) on MI355X.
//  x[2,2048,1024] fp32, Wqkv[1024,3072], Wo[1024,1024], tau[16]
// R9: attn drops K/V LDS staging + ALL main-loop barriers — K/V tiles are
//     L2-resident (re-read by 16 q-blocks; FETCH=70MB=compulsory), so frags
//     load straight from global (m169 lesson: don't stage what L2 holds).
//     Occupancy is hard-capped at 2 waves/SIMD by unified VGPR+AGPR regs
//     (R8 lesson), so the win must come from removing barrier-coupled
//     serial chains, not wave count. R8's KV-split/combine reverted (null).
// ---------------------------------------------------------------------------

typedef unsigned short ushort_t;
typedef __attribute__((ext_vector_type(8))) short short8;
typedef __attribute__((ext_vector_type(4))) float f32x4;
typedef __attribute__((ext_vector_type(16))) float f32x16;

#define B_      2
#define T_      2048
#define C_      1024
#define HEADS_  16
#define D_      64

union frag_u { unsigned u[4]; short8 s8; };

__device__ __forceinline__ ushort_t f2bf(float f) {
  __hip_bfloat16 h = __float2bfloat16(f);           // RNE
  return *reinterpret_cast<ushort_t*>(&h);
}

__device__ __forceinline__ unsigned cvt_pk_bf16(float lo, float hi) {
  unsigned r;
  asm("v_cvt_pk_bf16_f32 %0, %1, %2" : "=v"(r) : "v"(lo), "v"(hi));
  return r;
}

__device__ __forceinline__ void permlane32_swap(unsigned &a, unsigned &b) {
  asm volatile("v_permlane32_swap_b32 %0, %1" : "+v"(a), "+v"(b));
}

__device__ __forceinline__ f32x16 zero16() {
  f32x16 z;
#pragma unroll
  for (int i = 0; i < 16; ++i) z[i] = 0.f;
  return z;
}

// -------------------------- cast x (fp32 -> bf16) --------------------------
__global__ __launch_bounds__(256) void cast_x_kernel(const float* __restrict__ x,
                                                     ushort_t* __restrict__ xb) {
  int i = blockIdx.x * 256 + threadIdx.x;
  float4 f = ((const float4*)x)[i];
  ushort_t* o = xb + (size_t)i * 4;
  o[0] = f2bf(f.x); o[1] = f2bf(f.y); o[2] = f2bf(f.z); o[3] = f2bf(f.w);
}

// ------------------ transpose + cast weights (fp32->bf16) ------------------
__global__ __launch_bounds__(256) void transpose_cast_w(const float* __restrict__ in,
                                                        ushort_t* __restrict__ out,
                                                        int R, int Cc) {
  __shared__ float tile[64][65];
  int rb = blockIdx.y, cb = blockIdx.x;
  int c = threadIdx.x & 63;
  int r0 = threadIdx.x >> 6;
#pragma unroll
  for (int i = 0; i < 16; ++i) {
    int r = r0 + i * 4;
    tile[r][c] = in[(size_t)(rb * 64 + r) * Cc + cb * 64 + c];
  }
  __syncthreads();
#pragma unroll
  for (int i = 0; i < 16; ++i) {
    int r = r0 + i * 4;
    out[(size_t)(cb * 64 + r) * R + rb * 64 + c] = f2bf(tile[c][r]);
  }
}

// ------------------------- transpose v -> vT (bf16) ------------------------
__global__ __launch_bounds__(256) void transpose_v_kernel(const ushort_t* __restrict__ v,
                                                          ushort_t* __restrict__ vT) {
  __shared__ ushort_t tile[64][72];
  int bh = blockIdx.y, tb = blockIdx.x;
  int c = threadIdx.x & 63;
  int r0 = threadIdx.x >> 6;
#pragma unroll
  for (int i = 0; i < 16; ++i) {
    int r = r0 + i * 4;
    tile[r][c] = v[((size_t)bh * T_ + tb * 64 + r) * D_ + c];
  }
  __syncthreads();
#pragma unroll
  for (int i = 0; i < 16; ++i) {
    int r = r0 + i * 4;
    vT[((size_t)bh * D_ + r) * T_ + tb * 64 + c] = tile[c][r];
  }
}

// -------------------- shared GEMM mainloop (bf16 MFMA) ---------------------
__device__ __forceinline__ void gemm_tile(const ushort_t* __restrict__ A,
                                          const ushort_t* __restrict__ Bt,
                                          int K, int tm, int tn,
                                          ushort_t* lds, f32x4 acc[4][4]) {
  const int tid = threadIdx.x;
  const int lane = tid & 63, wave = tid >> 6;
  const int wm = wave >> 1, wn = wave & 1;
  const int lr = lane & 15, lk = lane >> 4;
  ushort_t* As = lds;               // [128][72]
  ushort_t* Bs = lds + 128 * 72;    // [128][72]
  const ushort_t* Ag = A + (size_t)tm * 128 * K;
  const ushort_t* Bg = Bt + (size_t)tn * 128 * K;

  for (int kt = 0; kt < K; kt += 64) {
#pragma unroll
    for (int i = 0; i < 4; ++i) {
      int cch = tid + i * 256; int row = cch >> 3, kc = cch & 7;
      *(short8*)&As[row * 72 + kc * 8] =
          *(const short8*)&Ag[(size_t)row * K + kt + kc * 8];
    }
#pragma unroll
    for (int i = 0; i < 4; ++i) {
      int cch = tid + i * 256; int row = cch >> 3, kc = cch & 7;
      *(short8*)&Bs[row * 72 + kc * 8] =
          *(const short8*)&Bg[(size_t)row * K + kt + kc * 8];
    }
    __syncthreads();
#pragma unroll
    for (int kk = 0; kk < 64; kk += 32) {
      short8 a[4], b[4];
#pragma unroll
      for (int m = 0; m < 4; ++m)
        a[m] = *(const short8*)&As[(wm * 64 + m * 16 + lr) * 72 + kk + lk * 8];
#pragma unroll
      for (int n = 0; n < 4; ++n)
        b[n] = *(const short8*)&Bs[(wn * 64 + n * 16 + lr) * 72 + kk + lk * 8];
#pragma unroll
      for (int m = 0; m < 4; ++m)
#pragma unroll
        for (int n = 0; n < 4; ++n)
          acc[m][n] = __builtin_amdgcn_mfma_f32_16x16x32_bf16(a[m], b[n], acc[m][n], 0, 0, 0);
    }
    __syncthreads();
  }
}

// -------------------- GEMM1: qkv = xb @ Wqkv^T, scatter --------------------
__global__ __launch_bounds__(256) void gemm_qkv(const ushort_t* __restrict__ xb,
                                                const ushort_t* __restrict__ wT,
                                                ushort_t* __restrict__ qg,
                                                ushort_t* __restrict__ kg,
                                                ushort_t* __restrict__ vg) {
  __shared__ __align__(16) ushort_t lds[2 * 128 * 72];
  f32x4 acc[4][4];
#pragma unroll
  for (int m = 0; m < 4; ++m)
#pragma unroll
    for (int n = 0; n < 4; ++n) acc[m][n] = (f32x4){0.f, 0.f, 0.f, 0.f};

  gemm_tile(xb, wT, C_, blockIdx.y, blockIdx.x, lds, acc);

  const int lane = threadIdx.x & 63, wave = threadIdx.x >> 6;
  const int wm = wave >> 1, wn = wave & 1;
  const int lr = lane & 15, lk = lane >> 4;
#pragma unroll
  for (int m = 0; m < 4; ++m)
#pragma unroll
    for (int n = 0; n < 4; ++n)
#pragma unroll
      for (int r = 0; r < 4; ++r) {
        int row = blockIdx.y * 128 + wm * 64 + m * 16 + lk * 4 + r;  // = b*T + t
        int col = blockIdx.x * 128 + wn * 64 + n * 16 + lr;          // [0,3072)
        int b = row >> 11, t = row & 2047;
        int part = col >> 10, idx = col & 1023;
        int h = idx >> 6, j = idx & 63;
        ushort_t* dst = (part == 0) ? qg : (part == 1) ? kg : vg;
        dst[(((size_t)(b * HEADS_ + h)) * T_ + t) * D_ + j] = f2bf(acc[m][n][r]);
      }
}

// ---------------------- GEMM2: out = attn_bf16 @ Wo^T ----------------------
__global__ __launch_bounds__(256) void gemm_out(const ushort_t* __restrict__ ab,
                                                const ushort_t* __restrict__ woT,
                                                float* __restrict__ out) {
  __shared__ __align__(16) ushort_t lds[2 * 128 * 72];
  f32x4 acc[4][4];
#pragma unroll
  for (int m = 0; m < 4; ++m)
#pragma unroll
    for (int n = 0; n < 4; ++n) acc[m][n] = (f32x4){0.f, 0.f, 0.f, 0.f};

  gemm_tile(ab, woT, C_, blockIdx.y, blockIdx.x, lds, acc);

  const int lane = threadIdx.x & 63, wave = threadIdx.x >> 6;
  const int wm = wave >> 1, wn = wave & 1;
  const int lr = lane & 15, lk = lane >> 4;
#pragma unroll
  for (int m = 0; m < 4; ++m)
#pragma unroll
    for (int n = 0; n < 4; ++n)
#pragma unroll
      for (int r = 0; r < 4; ++r) {
        int row = blockIdx.y * 128 + wm * 64 + m * 16 + lk * 4 + r;
        int col = blockIdx.x * 128 + wn * 64 + n * 16 + lr;
        out[(size_t)row * C_ + col] = acc[m][n][r];
      }
}

// --------------------------- fused 2quad attention -------------------------
// Block = (bh, 128 q-rows), 4 waves = 2 q-groups (wq) x 2 KV-splits (wk).
// NO K/V LDS staging, NO main-loop barriers: K-frags and V^T-frags are read
// directly from global per lane (16B each). K/V per bh = 512KB, re-read by
// 16 q-blocks -> L2-resident; the VMEM queue pipelines the latency and each
// wave runs the 16 KV rounds fully independently. LDS is only the epilogue
// combine buffer. Swapped QK^T (mfma(K,Q), 32x32x16), E in registers via
// cvt_pk_bf16 + permlane32_swap (layouts verified R3).
__global__ __launch_bounds__(256, 2) void attn_kernel(const ushort_t* __restrict__ qg,
                                                      const ushort_t* __restrict__ kg,
                                                      const ushort_t* __restrict__ vTg,
                                                      const float* __restrict__ tau,
                                                      ushort_t* __restrict__ attn_out) {
  __shared__ float out_lds[2 * 64 * 64];       // [wq][64 q][64 d] fp32 (32 KB)
  __shared__ float denom_lds[2][2][2][32];     // [wk][wq][qb][q]

  const int tid = threadIdx.x, lane = tid & 63;
  const int w = tid >> 6, wq = w >> 1, wk = w & 1;
  const int l31 = lane & 31, hi = lane >> 5, hi8 = hi * 8;
  const int qt = blockIdx.x, bh = blockIdx.y;
  const int b = bh >> 4, h = bh & 15;
  const float inv = 1.0f / (8.0f * tau[h]);   // sqrt(64)*tau

  const ushort_t* kb_ = kg  + (size_t)bh * T_ * D_;
  const ushort_t* vb_ = vTg + (size_t)bh * D_ * T_;
  const ushort_t* qp  = qg  + ((size_t)bh * T_ + qt * 128 + wq * 64) * D_;

  // Q B-frags in registers, loop-invariant.
  short8 qf[2][4];
#pragma unroll
  for (int qb = 0; qb < 2; ++qb)
#pragma unroll
    for (int dc = 0; dc < 4; ++dc)
      qf[qb][dc] = *(const short8*)&qp[(qb * 32 + l31) * D_ + dc * 16 + hi8];

  // per-lane base pointers for direct K/V fragment loads
  const ushort_t* kfp = kb_ + (size_t)(wk * 64 + l31) * D_ + hi8;         // + k*64 + dc*16
  const ushort_t* vfp = vb_ + (size_t)l31 * T_ + wk * 64 + hi8;           // + db*32*T + k + c*16

  f32x16 acc[2][2];   // [qb][db]: D[q=crow(r,hi)][d=db*32+l31]
  acc[0][0] = zero16(); acc[0][1] = zero16();
  acc[1][0] = zero16(); acc[1][1] = zero16();
  float denomp[2] = {0.f, 0.f};

  for (int rnd = 0; rnd < T_ / 128; ++rnd) {
    const int kv0 = rnd * 128;
#pragma unroll
    for (int kb = 0; kb < 2; ++kb) {
      const size_t koff = (size_t)(kv0 + kb * 32) * D_;   // k-row offset for K
      const size_t voff = (size_t)(kv0 + kb * 32);        // k-col offset for V^T

      // S^T = K-rows x Q-rows : D[k=crow(r,hi)][q=l31]
      f32x16 s[2]; s[0] = zero16(); s[1] = zero16();
#pragma unroll
      for (int dc = 0; dc < 4; ++dc) {
        short8 kf = *(const short8*)&kfp[koff + dc * 16];
        s[0] = __builtin_amdgcn_mfma_f32_32x32x16_bf16(kf, qf[0][dc], s[0], 0, 0, 0);
        s[1] = __builtin_amdgcn_mfma_f32_32x32x16_bf16(kf, qf[1][dc], s[1], 0, 0, 0);
      }

      // e = (s*inv+5)^2 in regs; reg-local denom; pack to PV A-frags
      frag_u ef[2][2];
#pragma unroll
      for (int qb = 0; qb < 2; ++qb) {
        float ev[16];
        float dsum = 0.f;
#pragma unroll
        for (int r = 0; r < 16; ++r) {
          float t = fmaf(s[qb][r], inv, 5.0f);
          ev[r] = t * t;
          dsum += ev[r];
        }
        denomp[qb] += dsum;
        unsigned P[8];
#pragma unroll
        for (int p = 0; p < 8; ++p) P[p] = cvt_pk_bf16(ev[2 * p], ev[2 * p + 1]);
        unsigned a0 = P[0], b0 = P[2]; permlane32_swap(a0, b0);
        unsigned a1 = P[1], b1 = P[3]; permlane32_swap(a1, b1);
        ef[qb][0].u[0] = a0; ef[qb][0].u[1] = a1; ef[qb][0].u[2] = b0; ef[qb][0].u[3] = b1;
        unsigned a2 = P[4], b2 = P[6]; permlane32_swap(a2, b2);
        unsigned a3 = P[5], b3 = P[7]; permlane32_swap(a3, b3);
        ef[qb][1].u[0] = a2; ef[qb][1].u[1] = a3; ef[qb][1].u[2] = b2; ef[qb][1].u[3] = b3;
      }

      // PV: acc[qb][db] += E[q][k-chunk] x V[k-chunk][d], V-frags from global
#pragma unroll
      for (int c = 0; c < 2; ++c)
#pragma unroll
        for (int db = 0; db < 2; ++db) {
          short8 vf = *(const short8*)&vfp[(size_t)(db * 32) * T_ + voff + c * 16];
          acc[0][db] = __builtin_amdgcn_mfma_f32_32x32x16_bf16(ef[0][c].s8, vf, acc[0][db], 0, 0, 0);
          acc[1][db] = __builtin_amdgcn_mfma_f32_32x32x16_bf16(ef[1][c].s8, vf, acc[1][db], 0, 0, 0);
        }
    }
  }

  // ---------------- epilogue: combine KV halves, normalize ----------------
#pragma unroll
  for (int qb = 0; qb < 2; ++qb) {
    float v = denomp[qb];
    v += __shfl_xor(v, 32);                    // combine hi halves
    if (lane < 32) denom_lds[wk][wq][qb][l31] = v;
  }
  if (wk == 1) {
#pragma unroll
    for (int qb = 0; qb < 2; ++qb)
#pragma unroll
      for (int db = 0; db < 2; ++db)
#pragma unroll
        for (int r = 0; r < 16; ++r) {
          int qr = qb * 32 + (r & 3) + 8 * (r >> 2) + 4 * hi;
          out_lds[(wq * 64 + qr) * 64 + db * 32 + l31] = acc[qb][db][r];
        }
  }
  __syncthreads();
  if (wk == 0) {
#pragma unroll
    for (int qb = 0; qb < 2; ++qb)
#pragma unroll
      for (int r = 0; r < 16; ++r) {
        int cr = (r & 3) + 8 * (r >> 2) + 4 * hi;
        int qr = qb * 32 + cr;
        float dt = denom_lds[0][wq][qb][cr] + denom_lds[1][wq][qb][cr];
        float dinv = 1.0f / (dt + 1e-6f);
#pragma unroll
        for (int db = 0; db < 2; ++db) {
          float val = acc[qb][db][r] + out_lds[(wq * 64 + qr) * 64 + db * 32 + l31];
          int grow = b * T_ + qt * 128 + wq * 64 + qr;
          attn_out[(size_t)grow * C_ + h * 64 + db * 32 + l31] = f2bf(val * dinv);
        }
      }
  }
}

// ---------------------------------------------------------------------------
extern "C" void kernel_launch(void* const* d_in, const int* in_sizes, int n_in,
                              void* d_out, int out_size, void* d_ws, size_t ws_size,
                              hipStream_t stream) {
  const float* x    = (const float*)d_in[0];
  const float* Wqkv = (const float*)d_in[1];
  const float* Wo   = (const float*)d_in[2];
  const float* tau  = (const float*)d_in[3];
  float* out = (float*)d_out;

  char* ws = (char*)d_ws;
  ushort_t* xb    = (ushort_t*)(ws);                 //  8,388,608 B
  ushort_t* wqkvT = (ushort_t*)(ws + 8388608);       //  6,291,456 B
  ushort_t* woT   = (ushort_t*)(ws + 14680064);      //  2,097,152 B
  ushort_t* qg    = (ushort_t*)(ws + 16777216);      //  8,388,608 B
  ushort_t* kg    = (ushort_t*)(ws + 25165824);      //  8,388,608 B
  ushort_t* ab    = (ushort_t*)(ws + 33554432);      //  8,388,608 B  (total ~42 MB)
  // v and vT scratch live in d_out (16,777,216 B) — consumed before gemm_out
  // overwrites d_out with the final fp32 result.
  ushort_t* vg  = (ushort_t*)d_out;
  ushort_t* vTg = (ushort_t*)d_out + 4194304;

  cast_x_kernel<<<4096, 256, 0, stream>>>(x, xb);
  transpose_cast_w<<<dim3(48, 16), 256, 0, stream>>>(Wqkv, wqkvT, 1024, 3072);
  transpose_cast_w<<<dim3(16, 16), 256, 0, stream>>>(Wo, woT, 1024, 1024);
  gemm_qkv<<<dim3(24, 32), 256, 0, stream>>>(xb, wqkvT, qg, kg, vg);
  transpose_v_kernel<<<dim3(32, 32), 256, 0, stream>>>(vg, vTg);
  attn_kernel<<<dim3(16, 32), 256, 0, stream>>>(qg, kg, vTg, tau, ab);
  gemm_out<<<dim3(8, 32), 256, 0, stream>>>(ab, woT, out);
}

// Round 10
// 126.346 us; speedup vs baseline: 1.2289x; 1.2289x over previous
//
#include <hip/hip_runtime.h>
#include <hip/hip_bf16.h>

// ---------------------------------------------------------------------------
// PlainSelfAttention (2quad, tau-scaled) on MI355X.
//  x[2,2048,1024] fp32, Wqkv[1024,3072], Wo[1024,1024], tau[16]
// R10: attn = R3/R7 proven structure + DOUBLE-BUFFERED K/V LDS -> ONE
//      barrier per KV round (was 2; the 2nd also drained the prefetch's
//      vmcnt). + s_setprio(1) around MFMA clusters (T5). R9's direct-global
//      frag reads reverted (non-coalesced, -57%). GEMMs untouched.
// ---------------------------------------------------------------------------

typedef unsigned short ushort_t;
typedef __attribute__((ext_vector_type(8))) short short8;
typedef __attribute__((ext_vector_type(4))) float f32x4;
typedef __attribute__((ext_vector_type(16))) float f32x16;

#define B_      2
#define T_      2048
#define C_      1024
#define HEADS_  16
#define D_      64

union frag_u { unsigned u[4]; short8 s8; };

__device__ __forceinline__ ushort_t f2bf(float f) {
  __hip_bfloat16 h = __float2bfloat16(f);           // RNE
  return *reinterpret_cast<ushort_t*>(&h);
}

__device__ __forceinline__ unsigned cvt_pk_bf16(float lo, float hi) {
  unsigned r;
  asm("v_cvt_pk_bf16_f32 %0, %1, %2" : "=v"(r) : "v"(lo), "v"(hi));
  return r;
}

__device__ __forceinline__ void permlane32_swap(unsigned &a, unsigned &b) {
  asm volatile("v_permlane32_swap_b32 %0, %1" : "+v"(a), "+v"(b));
}

__device__ __forceinline__ f32x16 zero16() {
  f32x16 z;
#pragma unroll
  for (int i = 0; i < 16; ++i) z[i] = 0.f;
  return z;
}

// -------------------------- cast x (fp32 -> bf16) --------------------------
__global__ __launch_bounds__(256) void cast_x_kernel(const float* __restrict__ x,
                                                     ushort_t* __restrict__ xb) {
  int i = blockIdx.x * 256 + threadIdx.x;
  float4 f = ((const float4*)x)[i];
  ushort_t* o = xb + (size_t)i * 4;
  o[0] = f2bf(f.x); o[1] = f2bf(f.y); o[2] = f2bf(f.z); o[3] = f2bf(f.w);
}

// ------------------ transpose + cast weights (fp32->bf16) ------------------
__global__ __launch_bounds__(256) void transpose_cast_w(const float* __restrict__ in,
                                                        ushort_t* __restrict__ out,
                                                        int R, int Cc) {
  __shared__ float tile[64][65];
  int rb = blockIdx.y, cb = blockIdx.x;
  int c = threadIdx.x & 63;
  int r0 = threadIdx.x >> 6;
#pragma unroll
  for (int i = 0; i < 16; ++i) {
    int r = r0 + i * 4;
    tile[r][c] = in[(size_t)(rb * 64 + r) * Cc + cb * 64 + c];
  }
  __syncthreads();
#pragma unroll
  for (int i = 0; i < 16; ++i) {
    int r = r0 + i * 4;
    out[(size_t)(cb * 64 + r) * R + rb * 64 + c] = f2bf(tile[c][r]);
  }
}

// ------------------------- transpose v -> vT (bf16) ------------------------
__global__ __launch_bounds__(256) void transpose_v_kernel(const ushort_t* __restrict__ v,
                                                          ushort_t* __restrict__ vT) {
  __shared__ ushort_t tile[64][72];
  int bh = blockIdx.y, tb = blockIdx.x;
  int c = threadIdx.x & 63;
  int r0 = threadIdx.x >> 6;
#pragma unroll
  for (int i = 0; i < 16; ++i) {
    int r = r0 + i * 4;
    tile[r][c] = v[((size_t)bh * T_ + tb * 64 + r) * D_ + c];
  }
  __syncthreads();
#pragma unroll
  for (int i = 0; i < 16; ++i) {
    int r = r0 + i * 4;
    vT[((size_t)bh * D_ + r) * T_ + tb * 64 + c] = tile[c][r];
  }
}

// -------------------- shared GEMM mainloop (bf16 MFMA) ---------------------
__device__ __forceinline__ void gemm_tile(const ushort_t* __restrict__ A,
                                          const ushort_t* __restrict__ Bt,
                                          int K, int tm, int tn,
                                          ushort_t* lds, f32x4 acc[4][4]) {
  const int tid = threadIdx.x;
  const int lane = tid & 63, wave = tid >> 6;
  const int wm = wave >> 1, wn = wave & 1;
  const int lr = lane & 15, lk = lane >> 4;
  ushort_t* As = lds;               // [128][72]
  ushort_t* Bs = lds + 128 * 72;    // [128][72]
  const ushort_t* Ag = A + (size_t)tm * 128 * K;
  const ushort_t* Bg = Bt + (size_t)tn * 128 * K;

  for (int kt = 0; kt < K; kt += 64) {
#pragma unroll
    for (int i = 0; i < 4; ++i) {
      int cch = tid + i * 256; int row = cch >> 3, kc = cch & 7;
      *(short8*)&As[row * 72 + kc * 8] =
          *(const short8*)&Ag[(size_t)row * K + kt + kc * 8];
    }
#pragma unroll
    for (int i = 0; i < 4; ++i) {
      int cch = tid + i * 256; int row = cch >> 3, kc = cch & 7;
      *(short8*)&Bs[row * 72 + kc * 8] =
          *(const short8*)&Bg[(size_t)row * K + kt + kc * 8];
    }
    __syncthreads();
#pragma unroll
    for (int kk = 0; kk < 64; kk += 32) {
      short8 a[4], b[4];
#pragma unroll
      for (int m = 0; m < 4; ++m)
        a[m] = *(const short8*)&As[(wm * 64 + m * 16 + lr) * 72 + kk + lk * 8];
#pragma unroll
      for (int n = 0; n < 4; ++n)
        b[n] = *(const short8*)&Bs[(wn * 64 + n * 16 + lr) * 72 + kk + lk * 8];
#pragma unroll
      for (int m = 0; m < 4; ++m)
#pragma unroll
        for (int n = 0; n < 4; ++n)
          acc[m][n] = __builtin_amdgcn_mfma_f32_16x16x32_bf16(a[m], b[n], acc[m][n], 0, 0, 0);
    }
    __syncthreads();
  }
}

// -------------------- GEMM1: qkv = xb @ Wqkv^T, scatter --------------------
__global__ __launch_bounds__(256) void gemm_qkv(const ushort_t* __restrict__ xb,
                                                const ushort_t* __restrict__ wT,
                                                ushort_t* __restrict__ qg,
                                                ushort_t* __restrict__ kg,
                                                ushort_t* __restrict__ vg) {
  __shared__ __align__(16) ushort_t lds[2 * 128 * 72];
  f32x4 acc[4][4];
#pragma unroll
  for (int m = 0; m < 4; ++m)
#pragma unroll
    for (int n = 0; n < 4; ++n) acc[m][n] = (f32x4){0.f, 0.f, 0.f, 0.f};

  gemm_tile(xb, wT, C_, blockIdx.y, blockIdx.x, lds, acc);

  const int lane = threadIdx.x & 63, wave = threadIdx.x >> 6;
  const int wm = wave >> 1, wn = wave & 1;
  const int lr = lane & 15, lk = lane >> 4;
#pragma unroll
  for (int m = 0; m < 4; ++m)
#pragma unroll
    for (int n = 0; n < 4; ++n)
#pragma unroll
      for (int r = 0; r < 4; ++r) {
        int row = blockIdx.y * 128 + wm * 64 + m * 16 + lk * 4 + r;  // = b*T + t
        int col = blockIdx.x * 128 + wn * 64 + n * 16 + lr;          // [0,3072)
        int b = row >> 11, t = row & 2047;
        int part = col >> 10, idx = col & 1023;
        int h = idx >> 6, j = idx & 63;
        ushort_t* dst = (part == 0) ? qg : (part == 1) ? kg : vg;
        dst[(((size_t)(b * HEADS_ + h)) * T_ + t) * D_ + j] = f2bf(acc[m][n][r]);
      }
}

// ---------------------- GEMM2: out = attn_bf16 @ Wo^T ----------------------
__global__ __launch_bounds__(256) void gemm_out(const ushort_t* __restrict__ ab,
                                                const ushort_t* __restrict__ woT,
                                                float* __restrict__ out) {
  __shared__ __align__(16) ushort_t lds[2 * 128 * 72];
  f32x4 acc[4][4];
#pragma unroll
  for (int m = 0; m < 4; ++m)
#pragma unroll
    for (int n = 0; n < 4; ++n) acc[m][n] = (f32x4){0.f, 0.f, 0.f, 0.f};

  gemm_tile(ab, woT, C_, blockIdx.y, blockIdx.x, lds, acc);

  const int lane = threadIdx.x & 63, wave = threadIdx.x >> 6;
  const int wm = wave >> 1, wn = wave & 1;
  const int lr = lane & 15, lk = lane >> 4;
#pragma unroll
  for (int m = 0; m < 4; ++m)
#pragma unroll
    for (int n = 0; n < 4; ++n)
#pragma unroll
      for (int r = 0; r < 4; ++r) {
        int row = blockIdx.y * 128 + wm * 64 + m * 16 + lk * 4 + r;
        int col = blockIdx.x * 128 + wn * 64 + n * 16 + lr;
        out[(size_t)row * C_ + col] = acc[m][n][r];
      }
}

// --------------------------- fused 2quad attention -------------------------
// Block = (bh, 128 q-rows), 4 waves = 2 q-groups (wq) x 2 KV-splits (wk),
// KV tile = 128k. Swapped QK^T (mfma(K,Q), 32x32x16), E in registers via
// cvt_pk_bf16 + permlane32_swap. R10: DOUBLE-BUFFERED K/V LDS -> one barrier
// per round: publish(t,buf[t&1]) -> barrier -> prefetch(t+1) -> compute(t).
// Next publish targets buf[(t+1)&1], so no trailing barrier is needed; a
// buffer can't be overwritten until every wave passed the barrier following
// its own compute on it. setprio(1) wraps the MFMA clusters (T5).
__global__ __launch_bounds__(256, 2) void attn_kernel(const ushort_t* __restrict__ qg,
                                                      const ushort_t* __restrict__ kg,
                                                      const ushort_t* __restrict__ vTg,
                                                      const float* __restrict__ tau,
                                                      ushort_t* __restrict__ attn_out) {
  // per buffer: Ks [128][72] (9216) | Vts [64][136] (8704) = 17920 ushorts
  __shared__ __align__(16) ushort_t kvbuf[2][17920];             // 71.7 KB
  __shared__ float denom_lds[2][2][2][32];                       // [wk][wq][qb][q]

  const int tid = threadIdx.x, lane = tid & 63;
  const int w = tid >> 6, wq = w >> 1, wk = w & 1;
  const int l31 = lane & 31, hi = lane >> 5, hi8 = hi * 8;
  const int qt = blockIdx.x, bh = blockIdx.y;
  const int b = bh >> 4, h = bh & 15;
  const float inv = 1.0f / (8.0f * tau[h]);   // sqrt(64)*tau

  const ushort_t* kb_ = kg  + (size_t)bh * T_ * D_;
  const ushort_t* vb_ = vTg + (size_t)bh * D_ * T_;
  const ushort_t* qp  = qg  + ((size_t)bh * T_ + qt * 128 + wq * 64) * D_;

  // per-thread staging coordinates (constant across tiles)
  const int krow[4] = { (tid) >> 3, (tid + 256) >> 3, (tid + 512) >> 3, (tid + 768) >> 3 };
  const int kcol = (tid & 7) * 8;
  const int vrow[4] = { (tid) >> 4, (tid + 256) >> 4, (tid + 512) >> 4, (tid + 768) >> 4 };
  const int vcol = (tid & 15) * 8;

  // Q B-frags in registers, loop-invariant.
  short8 qf[2][4];
#pragma unroll
  for (int qb = 0; qb < 2; ++qb)
#pragma unroll
    for (int dc = 0; dc < 4; ++dc)
      qf[qb][dc] = *(const short8*)&qp[(qb * 32 + l31) * D_ + dc * 16 + hi8];

  f32x16 acc[2][2];   // [qb][db]: D[q=crow(r,hi)][d=db*32+l31]
  acc[0][0] = zero16(); acc[0][1] = zero16();
  acc[1][0] = zero16(); acc[1][1] = zero16();
  float denomp[2] = {0.f, 0.f};

  // ---- prologue: load tile 0 into registers ----
  short8 kreg[4], vreg[4];
#pragma unroll
  for (int i = 0; i < 4; ++i) {
    kreg[i] = *(const short8*)&kb_[(size_t)krow[i] * D_ + kcol];
    vreg[i] = *(const short8*)&vb_[(size_t)vrow[i] * T_ + vcol];
  }

  const int NT = T_ / 128;
  for (int rnd = 0; rnd < NT; ++rnd) {
    ushort_t* Ks  = kvbuf[rnd & 1];
    ushort_t* Vts = kvbuf[rnd & 1] + 9216;

    // publish tile rnd from regs to this round's buffer
#pragma unroll
    for (int i = 0; i < 4; ++i) {
      *(short8*)&Ks[krow[i] * 72 + kcol] = kreg[i];
      *(short8*)&Vts[vrow[i] * 136 + vcol] = vreg[i];
    }
    __syncthreads();                           // the ONLY barrier per round

    // prefetch tile rnd+1 (consumed at next publish -> waitcnt after compute)
    if (rnd + 1 < NT) {
      const int kv0 = (rnd + 1) * 128;
#pragma unroll
      for (int i = 0; i < 4; ++i) {
        kreg[i] = *(const short8*)&kb_[(size_t)(kv0 + krow[i]) * D_ + kcol];
        vreg[i] = *(const short8*)&vb_[(size_t)vrow[i] * T_ + kv0 + vcol];
      }
    }

#pragma unroll
    for (int kb = 0; kb < 2; ++kb) {
      const int krow0 = wk * 64 + kb * 32;     // this wave's 32-k block
      // S^T = K-rows x Q-rows : D[k=crow(r,hi)][q=l31]
      f32x16 s[2]; s[0] = zero16(); s[1] = zero16();
      __builtin_amdgcn_s_setprio(1);
#pragma unroll
      for (int dc = 0; dc < 4; ++dc) {
        short8 kf = *(const short8*)&Ks[(krow0 + l31) * 72 + dc * 16 + hi8];
        s[0] = __builtin_amdgcn_mfma_f32_32x32x16_bf16(kf, qf[0][dc], s[0], 0, 0, 0);
        s[1] = __builtin_amdgcn_mfma_f32_32x32x16_bf16(kf, qf[1][dc], s[1], 0, 0, 0);
      }
      __builtin_amdgcn_s_setprio(0);

      // e = (s*inv+5)^2 in regs; reg-local denom; pack to PV A-frags
      frag_u ef[2][2];
#pragma unroll
      for (int qb = 0; qb < 2; ++qb) {
        float ev[16];
        float dsum = 0.f;
#pragma unroll
        for (int r = 0; r < 16; ++r) {
          float t = fmaf(s[qb][r], inv, 5.0f);
          ev[r] = t * t;
          dsum += ev[r];
        }
        denomp[qb] += dsum;
        unsigned P[8];
#pragma unroll
        for (int p = 0; p < 8; ++p) P[p] = cvt_pk_bf16(ev[2 * p], ev[2 * p + 1]);
        unsigned a0 = P[0], b0 = P[2]; permlane32_swap(a0, b0);
        unsigned a1 = P[1], b1 = P[3]; permlane32_swap(a1, b1);
        ef[qb][0].u[0] = a0; ef[qb][0].u[1] = a1; ef[qb][0].u[2] = b0; ef[qb][0].u[3] = b1;
        unsigned a2 = P[4], b2 = P[6]; permlane32_swap(a2, b2);
        unsigned a3 = P[5], b3 = P[7]; permlane32_swap(a3, b3);
        ef[qb][1].u[0] = a2; ef[qb][1].u[1] = a3; ef[qb][1].u[2] = b2; ef[qb][1].u[3] = b3;
      }

      // PV: acc[qb][db] += E[q][k-chunk] x V[k-chunk][d]
      __builtin_amdgcn_s_setprio(1);
#pragma unroll
      for (int c = 0; c < 2; ++c)
#pragma unroll
        for (int db = 0; db < 2; ++db) {
          short8 vf = *(const short8*)&Vts[(db * 32 + l31) * 136 + krow0 + c * 16 + hi8];
          acc[0][db] = __builtin_amdgcn_mfma_f32_32x32x16_bf16(ef[0][c].s8, vf, acc[0][db], 0, 0, 0);
          acc[1][db] = __builtin_amdgcn_mfma_f32_32x32x16_bf16(ef[1][c].s8, vf, acc[1][db], 0, 0, 0);
        }
      __builtin_amdgcn_s_setprio(0);
    }
    // no trailing barrier: next publish writes the other buffer
  }

  // ---------------- epilogue: combine KV halves, normalize ----------------
#pragma unroll
  for (int qb = 0; qb < 2; ++qb) {
    float v = denomp[qb];
    v += __shfl_xor(v, 32);                    // combine hi halves
    if (lane < 32) denom_lds[wk][wq][qb][l31] = v;
  }
  // out_lds reuses buf0 (last compute read buf1 since NT-1=15 is odd)
  float* out_lds = (float*)kvbuf[0];           // [2 wq][64 q][64 d] fp32 (32 KB)
  if (wk == 1) {
#pragma unroll
    for (int qb = 0; qb < 2; ++qb)
#pragma unroll
      for (int db = 0; db < 2; ++db)
#pragma unroll
        for (int r = 0; r < 16; ++r) {
          int qr = qb * 32 + (r & 3) + 8 * (r >> 2) + 4 * hi;
          out_lds[(wq * 64 + qr) * 64 + db * 32 + l31] = acc[qb][db][r];
        }
  }
  __syncthreads();
  if (wk == 0) {
#pragma unroll
    for (int qb = 0; qb < 2; ++qb)
#pragma unroll
      for (int r = 0; r < 16; ++r) {
        int cr = (r & 3) + 8 * (r >> 2) + 4 * hi;
        int qr = qb * 32 + cr;
        float dt = denom_lds[0][wq][qb][cr] + denom_lds[1][wq][qb][cr];
        float dinv = 1.0f / (dt + 1e-6f);
#pragma unroll
        for (int db = 0; db < 2; ++db) {
          float val = acc[qb][db][r] + out_lds[(wq * 64 + qr) * 64 + db * 32 + l31];
          int grow = b * T_ + qt * 128 + wq * 64 + qr;
          attn_out[(size_t)grow * C_ + h * 64 + db * 32 + l31] = f2bf(val * dinv);
        }
      }
  }
}

// ---------------------------------------------------------------------------
extern "C" void kernel_launch(void* const* d_in, const int* in_sizes, int n_in,
                              void* d_out, int out_size, void* d_ws, size_t ws_size,
                              hipStream_t stream) {
  const float* x    = (const float*)d_in[0];
  const float* Wqkv = (const float*)d_in[1];
  const float* Wo   = (const float*)d_in[2];
  const float* tau  = (const float*)d_in[3];
  float* out = (float*)d_out;

  char* ws = (char*)d_ws;
  ushort_t* xb    = (ushort_t*)(ws);                 //  8,388,608 B
  ushort_t* wqkvT = (ushort_t*)(ws + 8388608);       //  6,291,456 B
  ushort_t* woT   = (ushort_t*)(ws + 14680064);      //  2,097,152 B
  ushort_t* qg    = (ushort_t*)(ws + 16777216);      //  8,388,608 B
  ushort_t* kg    = (ushort_t*)(ws + 25165824);      //  8,388,608 B
  ushort_t* ab    = (ushort_t*)(ws + 33554432);      //  8,388,608 B  (total ~42 MB)
  // v and vT scratch live in d_out (16,777,216 B) — consumed before gemm_out
  // overwrites d_out with the final fp32 result.
  ushort_t* vg  = (ushort_t*)d_out;
  ushort_t* vTg = (ushort_t*)d_out + 4194304;

  cast_x_kernel<<<4096, 256, 0, stream>>>(x, xb);
  transpose_cast_w<<<dim3(48, 16), 256, 0, stream>>>(Wqkv, wqkvT, 1024, 3072);
  transpose_cast_w<<<dim3(16, 16), 256, 0, stream>>>(Wo, woT, 1024, 1024);
  gemm_qkv<<<dim3(24, 32), 256, 0, stream>>>(xb, wqkvT, qg, kg, vg);
  transpose_v_kernel<<<dim3(32, 32), 256, 0, stream>>>(vg, vTg);
  attn_kernel<<<dim3(16, 32), 256, 0, stream>>>(qg, kg, vTg, tau, ab);
  gemm_out<<<dim3(8, 32), 256, 0, stream>>>(ab, woT, out);
}